// Round 4
// baseline (832.731 us; speedup 1.0000x reference)
//
#include <hip/hip_runtime.h>

typedef short short8 __attribute__((ext_vector_type(8)));
typedef float float4v __attribute__((ext_vector_type(4)));
typedef unsigned int uint2v __attribute__((ext_vector_type(2)));

__device__ __forceinline__ unsigned short f2bf(float f) {
    unsigned int u = __float_as_uint(f);
    u += 0x7fffu + ((u >> 16) & 1u);   // RNE
    return (unsigned short)(u >> 16);
}
__device__ __forceinline__ float bfs(const unsigned short* p) {
    return __uint_as_float(((unsigned int)*p) << 16);
}
__device__ __forceinline__ float4v mfma16(short8 a, short8 b, float4v c) {
    return __builtin_amdgcn_mfma_f32_16x16x32_bf16(a, b, c, 0, 0, 0);
}
// strides 40B/72B/152B are only 8B-aligned: force 2x ds_read_b64, never b128
__device__ __forceinline__ short8 ld_b64x2(const unsigned short* p) {
    union { short8 s; uint2v u[2]; } r;
    r.u[0] = *(const uint2v*)(p);
    r.u[1] = *(const uint2v*)(p + 4);
    return r.s;
}

// pack qkv_w (288x96) / proj_w (96x96) fp32 -> bf16 MFMA A-fragment order
__global__ void prep_pack(const float* __restrict__ qkv_w,
                          const float* __restrict__ proj_w,
                          short* __restrict__ apq, short* __restrict__ app) {
    const int i = blockIdx.x * 256 + threadIdx.x;
    if (i < 3456) {
        const int rem = i % 192, f = rem / 64, lane = rem % 64;
        const int m = (i / 192) * 16 + (lane & 15);
        const int kb = f * 32 + ((lane >> 4) & 3) * 8;
        const float* s = qkv_w + m * 96 + kb;
        short8 o;
        #pragma unroll
        for (int j = 0; j < 8; ++j) o[j] = (short)f2bf(s[j]);
        *(short8*)(apq + i * 8) = o;
    } else if (i < 4608) {
        const int i2 = i - 3456;
        const int rem = i2 % 192, f = rem / 64, lane = rem % 64;
        const int m = (i2 / 192) * 16 + (lane & 15);
        const int kb = f * 32 + ((lane >> 4) & 3) * 8;
        const float* s = proj_w + m * 96 + kb;
        short8 o;
        #pragma unroll
        for (int j = 0; j < 8; ++j) o[j] = (short)f2bf(s[j]);
        *(short8*)(app + i2 * 8) = o;
    }
}

// One block per 8x8 window, 256 threads = 4 waves. LDS 32400 (-> 32768).
// Occupancy economics (rounds 1-3): kernel is barrier/latency-bound, so
// resident waves dominate. yacc[6] (24 f32 live all-kernel) pushed VGPR to
// 104 -> 4 waves/SIMD -> 16 waves/CU. Replacing it with per-head-pair
// global RMW on yout (race-free: each block owns its pixels; L2-hot:
// ~24.6KB/block re-touched within a head-pair) drops live set to ~82 ->
// organic VGPR <=102 -> 5 blocks/CU = 20 waves.
// NO min-waves hint: pinning halves the effective cap on this toolchain
// (observed 64 @ (256,4), 48 @ (256,5)) and causes scratch spills.
__global__ __launch_bounds__(256)
void fused_win_attn(const float* __restrict__ x,
                    const short* __restrict__ apq,
                    const float* __restrict__ qkv_b,
                    const float* __restrict__ dw_w,
                    const float* __restrict__ dw_b,
                    const short* __restrict__ app,
                    const float* __restrict__ proj_b,
                    const float* __restrict__ temperature,
                    const float* __restrict__ rel_bias,
                    float* __restrict__ yout)
{
    __shared__ __align__(16) unsigned char smem[32400];
    // Region X [0,13312) (time-multiplexed):
    //   sxT  [64][104] staging                    bytes [0,13312)
    //   raw  [48][91]  dwconv halo (P1W-P2R)      bytes [0,8736)
    //   sST  [64][76]  raw exp     (P3W-P5R)      bytes [0,9728)
    //   stmp [16][76]  tmp         (P4W-P5R)      bytes [9728,12160)
    //   ach  [16][24]  attn_ch     (P3W-P4R)      bytes [12160,12928)
    unsigned short* sxT   = (unsigned short*)smem;
    unsigned short* raw   = (unsigned short*)smem;
    unsigned short* sST   = (unsigned short*)smem;
    unsigned short* stmp  = (unsigned short*)(smem + 9728);
    unsigned short* ach   = (unsigned short*)(smem + 12160);
    unsigned short* sqkv  = (unsigned short*)(smem + 13312); // [32][64] XOR-swizzled
    unsigned short* qnT   = (unsigned short*)(smem + 17408); // [64][20]
    unsigned short* knT   = (unsigned short*)(smem + 19968); // [64][20]
    unsigned short* vT    = (unsigned short*)(smem + 22528); // [64][20]
    unsigned short* sbias = (unsigned short*)(smem + 25088); // [1352]
    unsigned short* outT  = (unsigned short*)(smem + 27792); // [64][36] head-pair out^T

    const int tid  = threadIdx.x;
    const int lane = tid & 63;
    const int g    = tid >> 6;
    const int quad = lane >> 4;
    const int l15  = lane & 15;
    const int wi = blockIdx.x;
    const int y0 = (wi >> 6) << 3;
    const int x0 = (wi & 63) << 3;
    const int py = lane >> 3, px = lane & 7;

    // ---- stage x^T (bf16) into region X; rel_bias bf16 ----
    for (int r = tid; r < 1536; r += 256) {
        const int c = r >> 4, p0 = (r & 15) * 4;
        float4 v = *(const float4*)(x + c * 262144 + (y0 + (p0 >> 3)) * 512 + x0 + (p0 & 7));
        sxT[(p0 + 0) * 104 + c] = f2bf(v.x);
        sxT[(p0 + 1) * 104 + c] = f2bf(v.y);
        sxT[(p0 + 2) * 104 + c] = f2bf(v.z);
        sxT[(p0 + 3) * 104 + c] = f2bf(v.w);
    }
    for (int r = tid; r < 1350; r += 256) sbias[r] = f2bf(rel_bias[r]);
    __syncthreads();

    // hoist qkv/proj B-fragments (same for all heads)
    short8 bfx[3];
    #pragma unroll
    for (int f = 0; f < 3; ++f)
        bfx[f] = *(const short8*)(sxT + (g * 16 + l15) * 104 + f * 32 + quad * 8);
    __syncthreads();   // region X now reusable

    for (int h = 0; h < 6; ++h) {
        // ---- P1: zero halo ring (27 cells/ch, shared L/R columns); qkv GEMM -> raw ----
        for (int r = tid; r < 1296; r += 256) {
            const int ch = r / 27, k = r % 27;
            int cell;
            if (k < 9)       cell = k;                 // top row
            else if (k < 18) cell = (k - 8) * 9;       // shared left/right column
            else             cell = 82 + (k - 18);     // bottom row
            raw[ch * 91 + cell] = 0;
        }
        {
            const int p = g * 16 + l15;
            const int wcell = (p >> 3) * 9 + (p & 7) + 10;
            #pragma unroll
            for (int t = 0; t < 3; ++t) {
                float4v acc = {0.f, 0.f, 0.f, 0.f};
                #pragma unroll
                for (int f = 0; f < 3; ++f) {
                    short8 af = *(const short8*)(apq + (((t * 6 + h) * 3 + f) * 64 + lane) * 8);
                    acc = mfma16(af, bfx[f], acc);
                }
                #pragma unroll
                for (int reg = 0; reg < 4; ++reg) {
                    const int rr = quad * 4 + reg;
                    raw[(t * 16 + rr) * 91 + wcell] =
                        f2bf(acc[reg] + qkv_b[t * 96 + h * 16 + rr]);
                }
            }
        }
        __syncthreads();   // B1

        // ---- P2: dwconv (91-stride halo reads) + L2 norm + transposes ----
        {
            unsigned int qw0 = 0, qw1 = 0, kw0 = 0, kw1 = 0, vw0 = 0, vw1 = 0;
            #pragma unroll
            for (int r = 0; r < 12; ++r) {
                const int j = (r >> 2) * 16 + 4 * g + (r & 3);   // wave-contig rows
                const int O = __builtin_amdgcn_readfirstlane((j >> 4) * 96 + h * 16 + (j & 15));
                const float* wq = dw_w + O * 9;
                float a = dw_b[O];
                const unsigned short* rbase = raw + j * 91 + py * 9 + px;
                a = fmaf(wq[0], bfs(rbase +  0), a);
                a = fmaf(wq[1], bfs(rbase +  1), a);
                a = fmaf(wq[2], bfs(rbase +  2), a);
                a = fmaf(wq[3], bfs(rbase +  9), a);
                a = fmaf(wq[4], bfs(rbase + 10), a);
                a = fmaf(wq[5], bfs(rbase + 11), a);
                a = fmaf(wq[6], bfs(rbase + 18), a);
                a = fmaf(wq[7], bfs(rbase + 19), a);
                a = fmaf(wq[8], bfs(rbase + 20), a);
                if (r < 8) {   // q,k rows: L2-normalize over N=64
                    float ss = a * a;
                    #pragma unroll
                    for (int m = 1; m < 64; m <<= 1) ss += __shfl_xor(ss, m, 64);
                    a = a * (1.f / fmaxf(sqrtf(ss), 1e-12f));
                    // ch-major copy for wave0's channel attention (XOR block swizzle)
                    sqkv[j * 64 + (lane ^ ((j & 7) * 8))] = f2bf(a);
                }
                const unsigned int bv = f2bf(a);
                if      (r == 0)  qw0 |= bv;          else if (r == 1)  qw0 |= bv << 16;
                else if (r == 2)  qw1 |= bv;          else if (r == 3)  qw1 |= bv << 16;
                else if (r == 4)  kw0 |= bv;          else if (r == 5)  kw0 |= bv << 16;
                else if (r == 6)  kw1 |= bv;          else if (r == 7)  kw1 |= bv << 16;
                else if (r == 8)  vw0 |= bv;          else if (r == 9)  vw0 |= bv << 16;
                else if (r == 10) vw1 |= bv;          else              vw1 |= bv << 16;
            }
            uint2v uq; uq.x = qw0; uq.y = qw1;
            uint2v uk; uk.x = kw0; uk.y = kw1;
            uint2v uv; uv.x = vw0; uv.y = vw1;
            *(uint2v*)(qnT + lane * 20 + 4 * g) = uq;   // stride 20: 4-way (opt) vs 16-way
            *(uint2v*)(knT + lane * 20 + 4 * g) = uk;
            *(uint2v*)(vT  + lane * 20 + 4 * g) = uv;
        }
        __syncthreads();   // B2

        // ---- P3: S^T logits; wave g owns n-block g for ALL m-tiles ->
        //          row sum l[n] completes in-register (sred eliminated). ----
        float lsum = 0.f;
        {
            short8 bq = {0, 0, 0, 0, 0, 0, 0, 0};
            if (lane < 32) bq = ld_b64x2(qnT + (g * 16 + l15) * 20 + quad * 8);
            #pragma unroll
            for (int mt = 0; mt < 4; ++mt) {
                short8 ak = {0, 0, 0, 0, 0, 0, 0, 0};
                if (lane < 32) ak = ld_b64x2(knT + (mt * 16 + l15) * 20 + quad * 8);
                float4v cs = {0.f, 0.f, 0.f, 0.f};
                cs = mfma16(ak, bq, cs);
                #pragma unroll
                for (int reg = 0; reg < 4; ++reg) {
                    const int m = mt * 16 + quad * 4 + reg;
                    const int n = g * 16 + l15;
                    const int idx = ((n >> 3) - (m >> 3) + 7) * 15 + ((n & 7) - (m & 7) + 7);
                    const float e = __expf(cs[reg] + bfs(sbias + idx * 6 + h));
                    sST[m * 76 + n] = f2bf(e);     // stride 76: conflict-free stores
                    lsum += e;
                }
            }
            lsum += __shfl_xor(lsum, 16, 64);
            lsum += __shfl_xor(lsum, 32, 64);      // all lanes: l[n], n = g*16+l15
        }
        if (g == 0) {
            const int sw = (l15 & 7) * 8;
            short8 a0 = *(const short8*)(sqkv + l15 * 64 + ((quad * 8) ^ sw));
            short8 a1 = *(const short8*)(sqkv + l15 * 64 + (((quad + 4) * 8) ^ sw));
            short8 b0 = *(const short8*)(sqkv + (16 + l15) * 64 + ((quad * 8) ^ sw));
            short8 b1 = *(const short8*)(sqkv + (16 + l15) * 64 + (((quad + 4) * 8) ^ sw));
            float4v cc = {0.f, 0.f, 0.f, 0.f};
            cc = mfma16(a0, b0, cc);
            cc = mfma16(a1, b1, cc);
            const float tp = temperature[h];
            #pragma unroll
            for (int reg = 0; reg < 4; ++reg) {
                const float e = __expf(cc[reg] * tp);
                float se = e;
                #pragma unroll
                for (int m = 1; m < 16; m <<= 1) se += __shfl_xor(se, m, 64);
                ach[(quad * 4 + reg) * 24 + l15] = f2bf(e / se);
            }
        }
        __syncthreads();   // B3

        // ---- P4: tmp = (attn_ch @ v) / l[n] -> stmp (l from register) ----
        {
            const float inv = 1.f / lsum;
            short8 af = {0, 0, 0, 0, 0, 0, 0, 0}, bv = {0, 0, 0, 0, 0, 0, 0, 0};
            if (lane < 32) {
                af = *(const short8*)(ach + l15 * 24 + quad * 8);
                bv = ld_b64x2(vT + (g * 16 + l15) * 20 + quad * 8);
            }
            float4v ct = {0.f, 0.f, 0.f, 0.f};
            ct = mfma16(af, bv, ct);
            #pragma unroll
            for (int reg = 0; reg < 4; ++reg)
                stmp[(quad * 4 + reg) * 76 + g * 16 + l15] = f2bf(ct[reg] * inv);
        }
        __syncthreads();   // B4

        // ---- P5: out_h^T = (tmp @ S)^T -> outT column half (h&1) ----
        {
            short8 a0 = ld_b64x2(stmp + l15 * 76 + quad * 8);
            short8 a1 = ld_b64x2(stmp + l15 * 76 + 32 + quad * 8);
            short8 b0 = ld_b64x2(sST + (g * 16 + l15) * 76 + quad * 8);
            short8 b1 = ld_b64x2(sST + (g * 16 + l15) * 76 + 32 + quad * 8);
            float4v co = {0.f, 0.f, 0.f, 0.f};
            co = mfma16(a0, b0, co);
            co = mfma16(a1, b1, co);
            #pragma unroll
            for (int reg = 0; reg < 4; ++reg)
                outT[(g * 16 + l15) * 36 + (h & 1) * 16 + quad * 4 + reg] = f2bf(co[reg]);
        }
        __syncthreads();   // B5 (protects region X + outT for what follows)

        // ---- P6 (after odd heads): yout(+)= W[:, 32*hp .. +32] @ [out_h-1 | out_h]
        //      app fragment f==hp covers exactly this K=32 slice: no repack.
        //      hp==0 overwrites (+bias); hp>=1 read-modify-write. Race-free:
        //      each thread owns its (channel,pixel) cells across all hp.
        //      Per-mt yprev staging keeps transient VGPR spike to +4. ----
        if (h & 1) {
            const int hp = h >> 1;
            short8 bo = ld_b64x2(outT + (g * 16 + l15) * 36 + quad * 8);
            const int p = g * 16 + l15;
            float* outbase = yout + (y0 + (p >> 3)) * 512 + x0 + (p & 7);
            #pragma unroll
            for (int mt = 0; mt < 6; ++mt) {
                short8 af = *(const short8*)(app + ((mt * 3 + hp) * 64 + lane) * 8);
                float yprev[4];
                if (hp) {
                    #pragma unroll
                    for (int reg = 0; reg < 4; ++reg)
                        yprev[reg] = outbase[(mt * 16 + quad * 4 + reg) * 262144];
                } else {
                    #pragma unroll
                    for (int reg = 0; reg < 4; ++reg)
                        yprev[reg] = proj_b[mt * 16 + quad * 4 + reg];
                }
                float4v pacc = {0.f, 0.f, 0.f, 0.f};
                pacc = mfma16(af, bo, pacc);
                #pragma unroll
                for (int reg = 0; reg < 4; ++reg)
                    outbase[(mt * 16 + quad * 4 + reg) * 262144] = pacc[reg] + yprev[reg];
            }
        }
    }
}

extern "C" void kernel_launch(void* const* d_in, const int* in_sizes, int n_in,
                              void* d_out, int out_size, void* d_ws, size_t ws_size,
                              hipStream_t stream) {
    const float* x      = (const float*)d_in[0];
    const float* qkv_w  = (const float*)d_in[1];
    const float* qkv_b  = (const float*)d_in[2];
    const float* dw_w   = (const float*)d_in[3];
    const float* dw_b   = (const float*)d_in[4];
    const float* proj_w = (const float*)d_in[5];
    const float* proj_b = (const float*)d_in[6];
    const float* temp   = (const float*)d_in[7];
    const float* relb   = (const float*)d_in[8];
    float* o = (float*)d_out;

    short* apq = (short*)d_ws;              // 27648 bf16
    short* app = apq + 27648;               // 9216 bf16

    hipLaunchKernelGGL(prep_pack, dim3(18), dim3(256), 0, stream, qkv_w, proj_w, apq, app);
    hipLaunchKernelGGL(fused_win_attn, dim3(4096), dim3(256), 0, stream,
                       x, apq, qkv_b, dw_w, dw_b, app, proj_b, temp, relb, o);
}

// Round 5
// 618.300 us; speedup vs baseline: 1.3468x; 1.3468x over previous
//
#include <hip/hip_runtime.h>

typedef short short8 __attribute__((ext_vector_type(8)));
typedef float float4v __attribute__((ext_vector_type(4)));
typedef unsigned int uint2v __attribute__((ext_vector_type(2)));

__device__ __forceinline__ unsigned short f2bf(float f) {
    unsigned int u = __float_as_uint(f);
    u += 0x7fffu + ((u >> 16) & 1u);   // RNE
    return (unsigned short)(u >> 16);
}
__device__ __forceinline__ float bfs(const unsigned short* p) {
    return __uint_as_float(((unsigned int)*p) << 16);
}
__device__ __forceinline__ float4v mfma16(short8 a, short8 b, float4v c) {
    return __builtin_amdgcn_mfma_f32_16x16x32_bf16(a, b, c, 0, 0, 0);
}
// rows with 8B-only alignment (strides 40B/152B/200B): 2x ds_read_b64, never b128
__device__ __forceinline__ short8 ld_b64x2(const unsigned short* p) {
    union { short8 s; uint2v u[2]; } r;
    r.u[0] = *(const uint2v*)(p);
    r.u[1] = *(const uint2v*)(p + 4);
    return r.s;
}

// pack qkv_w (288x96) / proj_w (96x96) fp32 -> bf16 MFMA A-fragment order
__global__ void prep_pack(const float* __restrict__ qkv_w,
                          const float* __restrict__ proj_w,
                          short* __restrict__ apq, short* __restrict__ app) {
    const int i = blockIdx.x * 256 + threadIdx.x;
    if (i < 3456) {
        const int rem = i % 192, f = rem / 64, lane = rem % 64;
        const int m = (i / 192) * 16 + (lane & 15);
        const int kb = f * 32 + ((lane >> 4) & 3) * 8;
        const float* s = qkv_w + m * 96 + kb;
        short8 o;
        #pragma unroll
        for (int j = 0; j < 8; ++j) o[j] = (short)f2bf(s[j]);
        *(short8*)(apq + i * 8) = o;
    } else if (i < 4608) {
        const int i2 = i - 3456;
        const int rem = i2 % 192, f = rem / 64, lane = rem % 64;
        const int m = (i2 / 192) * 16 + (lane & 15);
        const int kb = f * 32 + ((lane >> 4) & 3) * 8;
        const float* s = proj_w + m * 96 + kb;
        short8 o;
        #pragma unroll
        for (int j = 0; j < 8; ++j) o[j] = (short)f2bf(s[j]);
        *(short8*)(app + i2 * 8) = o;
    }
}

// One block per 8x8 window, 256 threads = 4 waves. LDS 40208 -> 4 blocks/CU.
// Occupancy economics learned in rounds 1-4: wave slots step at VGPR 64/128;
// any VGPR in (64,128] gives 4 waves/SIMD = 16 waves/CU — identical to the
// LDS cap at 4 blocks. So: round-0 register-light structure (soutT in LDS,
// proj epilogue; fused-proj variants spill/lose waves/leak HBM), organic
// allocation (NO min-waves pin: pinning makes the allocator clamp to 64/48
// and spill ~29 dwords/thread), plus the register-neutral LDS wins:
//   qnT/knT/vT stride 20 (16-way -> 4-way), sST/stmp stride 76 (clean),
//   sqkv XOR-swizzle, lsum in-register (sred gone), 91-stride raw halo,
//   sxT/soutT stride 100 (conflict-free b64 rows, -1 KiB).
__global__ __launch_bounds__(256)
void fused_win_attn(const float* __restrict__ x,
                    const short* __restrict__ apq,
                    const float* __restrict__ qkv_b,
                    const float* __restrict__ dw_w,
                    const float* __restrict__ dw_b,
                    const short* __restrict__ app,
                    const float* __restrict__ proj_b,
                    const float* __restrict__ temperature,
                    const float* __restrict__ rel_bias,
                    float* __restrict__ yout)
{
    __shared__ __align__(16) unsigned char smem[40208];
    // Region X [0,12928) (time-multiplexed):
    //   sxT  [64][100] staging                    bytes [0,12800)
    //   raw  [48][91]  dwconv halo (P1W-P2R)      bytes [0,8736)
    //   sST  [64][76]  raw exp     (P3W-P5R)      bytes [0,9728)
    //   stmp [16][76]  tmp         (P4W-P5R)      bytes [9728,12160)
    //   ach  [16][24]  attn_ch     (P3W-P4R)      bytes [12160,12928)
    unsigned short* sxT   = (unsigned short*)smem;
    unsigned short* raw   = (unsigned short*)smem;
    unsigned short* sST   = (unsigned short*)smem;
    unsigned short* stmp  = (unsigned short*)(smem + 9728);
    unsigned short* ach   = (unsigned short*)(smem + 12160);
    unsigned short* soutT = (unsigned short*)(smem + 12928); // [64][100] persistent
    unsigned short* sqkv  = (unsigned short*)(smem + 25728); // [32][64] XOR-swizzled
    unsigned short* qnT   = (unsigned short*)(smem + 29824); // [64][20]
    unsigned short* knT   = (unsigned short*)(smem + 32384); // [64][20]
    unsigned short* vT    = (unsigned short*)(smem + 34944); // [64][20]
    unsigned short* sbias = (unsigned short*)(smem + 37504); // [1352]

    const int tid  = threadIdx.x;
    const int lane = tid & 63;
    const int g    = tid >> 6;
    const int quad = lane >> 4;
    const int l15  = lane & 15;
    const int wi = blockIdx.x;
    const int y0 = (wi >> 6) << 3;
    const int x0 = (wi & 63) << 3;
    const int py = lane >> 3, px = lane & 7;

    // ---- stage x^T (bf16) into region X; rel_bias bf16 ----
    for (int r = tid; r < 1536; r += 256) {
        const int c = r >> 4, p0 = (r & 15) * 4;
        float4 v = *(const float4*)(x + c * 262144 + (y0 + (p0 >> 3)) * 512 + x0 + (p0 & 7));
        sxT[(p0 + 0) * 100 + c] = f2bf(v.x);
        sxT[(p0 + 1) * 100 + c] = f2bf(v.y);
        sxT[(p0 + 2) * 100 + c] = f2bf(v.z);
        sxT[(p0 + 3) * 100 + c] = f2bf(v.w);
    }
    for (int r = tid; r < 1350; r += 256) sbias[r] = f2bf(rel_bias[r]);
    __syncthreads();

    // hoist qkv B-fragments (same for all heads)
    short8 bfx[3];
    #pragma unroll
    for (int f = 0; f < 3; ++f)
        bfx[f] = ld_b64x2(sxT + (g * 16 + l15) * 100 + f * 32 + quad * 8);
    __syncthreads();   // region X now reusable

    for (int h = 0; h < 6; ++h) {
        // ---- P1: zero halo ring (27 cells/ch, shared L/R columns); qkv GEMM -> raw ----
        for (int r = tid; r < 1296; r += 256) {
            const int ch = r / 27, k = r % 27;
            int cell;
            if (k < 9)       cell = k;                 // top row
            else if (k < 18) cell = (k - 8) * 9;       // shared left/right column
            else             cell = 82 + (k - 18);     // bottom row
            raw[ch * 91 + cell] = 0;
        }
        {
            const int p = g * 16 + l15;
            const int wcell = (p >> 3) * 9 + (p & 7) + 10;
            #pragma unroll
            for (int t = 0; t < 3; ++t) {
                float4v acc = {0.f, 0.f, 0.f, 0.f};
                #pragma unroll
                for (int f = 0; f < 3; ++f) {
                    short8 af = *(const short8*)(apq + (((t * 6 + h) * 3 + f) * 64 + lane) * 8);
                    acc = mfma16(af, bfx[f], acc);
                }
                #pragma unroll
                for (int reg = 0; reg < 4; ++reg) {
                    const int rr = quad * 4 + reg;
                    raw[(t * 16 + rr) * 91 + wcell] =
                        f2bf(acc[reg] + qkv_b[t * 96 + h * 16 + rr]);
                }
            }
        }
        __syncthreads();   // B1

        // ---- P2: dwconv (91-stride halo reads) + L2 norm + transposes ----
        {
            unsigned int qw0 = 0, qw1 = 0, kw0 = 0, kw1 = 0, vw0 = 0, vw1 = 0;
            #pragma unroll
            for (int r = 0; r < 12; ++r) {
                const int j = (r >> 2) * 16 + 4 * g + (r & 3);   // wave-contig rows
                const int O = __builtin_amdgcn_readfirstlane((j >> 4) * 96 + h * 16 + (j & 15));
                const float* wq = dw_w + O * 9;
                float a = dw_b[O];
                const unsigned short* rbase = raw + j * 91 + py * 9 + px;
                a = fmaf(wq[0], bfs(rbase +  0), a);
                a = fmaf(wq[1], bfs(rbase +  1), a);
                a = fmaf(wq[2], bfs(rbase +  2), a);
                a = fmaf(wq[3], bfs(rbase +  9), a);
                a = fmaf(wq[4], bfs(rbase + 10), a);
                a = fmaf(wq[5], bfs(rbase + 11), a);
                a = fmaf(wq[6], bfs(rbase + 18), a);
                a = fmaf(wq[7], bfs(rbase + 19), a);
                a = fmaf(wq[8], bfs(rbase + 20), a);
                if (r < 8) {   // q,k rows: L2-normalize over N=64
                    float ss = a * a;
                    #pragma unroll
                    for (int m = 1; m < 64; m <<= 1) ss += __shfl_xor(ss, m, 64);
                    a = a * (1.f / fmaxf(sqrtf(ss), 1e-12f));
                    // ch-major copy for wave0's channel attention (XOR block swizzle)
                    sqkv[j * 64 + (lane ^ ((j & 7) * 8))] = f2bf(a);
                }
                const unsigned int bv = f2bf(a);
                if      (r == 0)  qw0 |= bv;          else if (r == 1)  qw0 |= bv << 16;
                else if (r == 2)  qw1 |= bv;          else if (r == 3)  qw1 |= bv << 16;
                else if (r == 4)  kw0 |= bv;          else if (r == 5)  kw0 |= bv << 16;
                else if (r == 6)  kw1 |= bv;          else if (r == 7)  kw1 |= bv << 16;
                else if (r == 8)  vw0 |= bv;          else if (r == 9)  vw0 |= bv << 16;
                else if (r == 10) vw1 |= bv;          else              vw1 |= bv << 16;
            }
            uint2v uq; uq.x = qw0; uq.y = qw1;
            uint2v uk; uk.x = kw0; uk.y = kw1;
            uint2v uv; uv.x = vw0; uv.y = vw1;
            *(uint2v*)(qnT + lane * 20 + 4 * g) = uq;   // stride 20: 4-way (opt) vs 16-way
            *(uint2v*)(knT + lane * 20 + 4 * g) = uk;
            *(uint2v*)(vT  + lane * 20 + 4 * g) = uv;
        }
        __syncthreads();   // B2

        // ---- P3: S^T logits; wave g owns n-block g for ALL m-tiles ->
        //          row sum l[n] completes in-register (sred eliminated). ----
        float lsum = 0.f;
        {
            short8 bq = {0, 0, 0, 0, 0, 0, 0, 0};
            if (lane < 32) bq = ld_b64x2(qnT + (g * 16 + l15) * 20 + quad * 8);
            #pragma unroll
            for (int mt = 0; mt < 4; ++mt) {
                short8 ak = {0, 0, 0, 0, 0, 0, 0, 0};
                if (lane < 32) ak = ld_b64x2(knT + (mt * 16 + l15) * 20 + quad * 8);
                float4v cs = {0.f, 0.f, 0.f, 0.f};
                cs = mfma16(ak, bq, cs);
                #pragma unroll
                for (int reg = 0; reg < 4; ++reg) {
                    const int m = mt * 16 + quad * 4 + reg;
                    const int n = g * 16 + l15;
                    const int idx = ((n >> 3) - (m >> 3) + 7) * 15 + ((n & 7) - (m & 7) + 7);
                    const float e = __expf(cs[reg] + bfs(sbias + idx * 6 + h));
                    sST[m * 76 + n] = f2bf(e);     // stride 76: conflict-free stores
                    lsum += e;
                }
            }
            lsum += __shfl_xor(lsum, 16, 64);
            lsum += __shfl_xor(lsum, 32, 64);      // all lanes: l[n], n = g*16+l15
        }
        if (g == 0) {
            const int sw = (l15 & 7) * 8;
            short8 a0 = *(const short8*)(sqkv + l15 * 64 + ((quad * 8) ^ sw));
            short8 a1 = *(const short8*)(sqkv + l15 * 64 + (((quad + 4) * 8) ^ sw));
            short8 b0 = *(const short8*)(sqkv + (16 + l15) * 64 + ((quad * 8) ^ sw));
            short8 b1 = *(const short8*)(sqkv + (16 + l15) * 64 + (((quad + 4) * 8) ^ sw));
            float4v cc = {0.f, 0.f, 0.f, 0.f};
            cc = mfma16(a0, b0, cc);
            cc = mfma16(a1, b1, cc);
            const float tp = temperature[h];
            #pragma unroll
            for (int reg = 0; reg < 4; ++reg) {
                const float e = __expf(cc[reg] * tp);
                float se = e;
                #pragma unroll
                for (int m = 1; m < 16; m <<= 1) se += __shfl_xor(se, m, 64);
                ach[(quad * 4 + reg) * 24 + l15] = f2bf(e / se);
            }
        }
        __syncthreads();   // B3

        // ---- P4: tmp = (attn_ch @ v) / l[n] -> stmp (l from register) ----
        {
            const float inv = 1.f / lsum;
            short8 af = {0, 0, 0, 0, 0, 0, 0, 0}, bv = {0, 0, 0, 0, 0, 0, 0, 0};
            if (lane < 32) {
                af = *(const short8*)(ach + l15 * 24 + quad * 8);
                bv = ld_b64x2(vT + (g * 16 + l15) * 20 + quad * 8);
            }
            float4v ct = {0.f, 0.f, 0.f, 0.f};
            ct = mfma16(af, bv, ct);
            #pragma unroll
            for (int reg = 0; reg < 4; ++reg)
                stmp[(quad * 4 + reg) * 76 + g * 16 + l15] = f2bf(ct[reg] * inv);
        }
        __syncthreads();   // B4

        // ---- P5: out_h^T = (tmp @ S)^T -> soutT column h ----
        {
            short8 a0 = ld_b64x2(stmp + l15 * 76 + quad * 8);
            short8 a1 = ld_b64x2(stmp + l15 * 76 + 32 + quad * 8);
            short8 b0 = ld_b64x2(sST + (g * 16 + l15) * 76 + quad * 8);
            short8 b1 = ld_b64x2(sST + (g * 16 + l15) * 76 + 32 + quad * 8);
            float4v co = {0.f, 0.f, 0.f, 0.f};
            co = mfma16(a0, b0, co);
            co = mfma16(a1, b1, co);
            #pragma unroll
            for (int reg = 0; reg < 4; ++reg)
                soutT[(g * 16 + l15) * 100 + h * 16 + quad * 4 + reg] = f2bf(co[reg]);
        }
        __syncthreads();   // B5 (protects region X for next head)
    }

    // ---- proj GEMM (96x64, K=96) + bias + window-reverse store ----
    {
        short8 pb[3];
        #pragma unroll
        for (int f = 0; f < 3; ++f)
            pb[f] = ld_b64x2(soutT + (g * 16 + l15) * 100 + f * 32 + quad * 8);
        const int p = g * 16 + l15;
        float* outbase = yout + (y0 + (p >> 3)) * 512 + x0 + (p & 7);
        #pragma unroll
        for (int mt = 0; mt < 6; ++mt) {
            float4v acc = {0.f, 0.f, 0.f, 0.f};
            #pragma unroll
            for (int f = 0; f < 3; ++f) {
                short8 af = *(const short8*)(app + ((mt * 3 + f) * 64 + lane) * 8);
                acc = mfma16(af, pb[f], acc);
            }
            #pragma unroll
            for (int reg = 0; reg < 4; ++reg) {
                const int o = mt * 16 + quad * 4 + reg;
                outbase[o * 262144] = acc[reg] + proj_b[o];
            }
        }
    }
}

extern "C" void kernel_launch(void* const* d_in, const int* in_sizes, int n_in,
                              void* d_out, int out_size, void* d_ws, size_t ws_size,
                              hipStream_t stream) {
    const float* x      = (const float*)d_in[0];
    const float* qkv_w  = (const float*)d_in[1];
    const float* qkv_b  = (const float*)d_in[2];
    const float* dw_w   = (const float*)d_in[3];
    const float* dw_b   = (const float*)d_in[4];
    const float* proj_w = (const float*)d_in[5];
    const float* proj_b = (const float*)d_in[6];
    const float* temp   = (const float*)d_in[7];
    const float* relb   = (const float*)d_in[8];
    float* o = (float*)d_out;

    short* apq = (short*)d_ws;              // 27648 bf16
    short* app = apq + 27648;               // 9216 bf16

    hipLaunchKernelGGL(prep_pack, dim3(18), dim3(256), 0, stream, qkv_w, proj_w, apq, app);
    hipLaunchKernelGGL(fused_win_attn, dim3(4096), dim3(256), 0, stream,
                       x, apq, qkv_b, dw_w, dw_b, app, proj_b, temp, relb, o);
}

// Round 6
// 555.394 us; speedup vs baseline: 1.4994x; 1.1133x over previous
//
#include <hip/hip_runtime.h>

typedef short short8 __attribute__((ext_vector_type(8)));
typedef float float4v __attribute__((ext_vector_type(4)));
typedef unsigned int uint2v __attribute__((ext_vector_type(2)));

__device__ __forceinline__ unsigned short f2bf(float f) {
    unsigned int u = __float_as_uint(f);
    u += 0x7fffu + ((u >> 16) & 1u);   // RNE
    return (unsigned short)(u >> 16);
}
__device__ __forceinline__ float bfs(const unsigned short* p) {
    return __uint_as_float(((unsigned int)*p) << 16);
}
// HW packed f32->bf16 (RNE): lo16 = bf16(a), hi16 = bf16(b). 1 VALU op vs ~8-10
// for two software f2bf. No builtin on gfx950 -> inline asm (non-volatile: pure
// VALU, dep-tracked through operands, schedulable/CSE-able).
__device__ __forceinline__ unsigned int pk2bf(float a, float b) {
    unsigned int r;
    asm("v_cvt_pk_bf16_f32 %0, %1, %2" : "=v"(r) : "v"(a), "v"(b));
    return r;
}
__device__ __forceinline__ float4v mfma16(short8 a, short8 b, float4v c) {
    return __builtin_amdgcn_mfma_f32_16x16x32_bf16(a, b, c, 0, 0, 0);
}
// rows with 8B-only alignment (strides 40B/152B/200B): 2x ds_read_b64, never b128
__device__ __forceinline__ short8 ld_b64x2(const unsigned short* p) {
    union { short8 s; uint2v u[2]; } r;
    r.u[0] = *(const uint2v*)(p);
    r.u[1] = *(const uint2v*)(p + 4);
    return r.s;
}

// pack qkv_w (288x96) / proj_w (96x96) fp32 -> bf16 MFMA A-fragment order
__global__ void prep_pack(const float* __restrict__ qkv_w,
                          const float* __restrict__ proj_w,
                          short* __restrict__ apq, short* __restrict__ app) {
    const int i = blockIdx.x * 256 + threadIdx.x;
    if (i < 3456) {
        const int rem = i % 192, f = rem / 64, lane = rem % 64;
        const int m = (i / 192) * 16 + (lane & 15);
        const int kb = f * 32 + ((lane >> 4) & 3) * 8;
        const float* s = qkv_w + m * 96 + kb;
        short8 o;
        #pragma unroll
        for (int j = 0; j < 8; ++j) o[j] = (short)f2bf(s[j]);
        *(short8*)(apq + i * 8) = o;
    } else if (i < 4608) {
        const int i2 = i - 3456;
        const int rem = i2 % 192, f = rem / 64, lane = rem % 64;
        const int m = (i2 / 192) * 16 + (lane & 15);
        const int kb = f * 32 + ((lane >> 4) & 3) * 8;
        const float* s = proj_w + m * 96 + kb;
        short8 o;
        #pragma unroll
        for (int j = 0; j < 8; ++j) o[j] = (short)f2bf(s[j]);
        *(short8*)(app + i2 * 8) = o;
    }
}

// One block per 8x8 window, 256 threads = 4 waves. LDS 40208 -> 4 blocks/CU.
// Occupancy is structurally 16 waves/CU (LDS 4-block cap; VGPR<=128 fine; the
// 5-block LDS squeeze is unreachable with soutT persistent and round-2 showed
// 5x32768 doesn't materialize anyway). NO min-waves pin (pinning -> 64/48 VGPR
// clamp + scratch spills). This round: VALU-path reduction — v_cvt_pk_bf16_f32
// for all paired f32->bf16, exp2-folded bias (sbias prescaled by log2e),
// v_rcp/v_rsq for divides/norm, b64-vectorized soutT store.
__global__ __launch_bounds__(256)
void fused_win_attn(const float* __restrict__ x,
                    const short* __restrict__ apq,
                    const float* __restrict__ qkv_b,
                    const float* __restrict__ dw_w,
                    const float* __restrict__ dw_b,
                    const short* __restrict__ app,
                    const float* __restrict__ proj_b,
                    const float* __restrict__ temperature,
                    const float* __restrict__ rel_bias,
                    float* __restrict__ yout)
{
    __shared__ __align__(16) unsigned char smem[40208];
    // Region X [0,12928) (time-multiplexed):
    //   sxT  [64][100] staging                    bytes [0,12800)
    //   raw  [48][91]  dwconv halo (P1W-P2R)      bytes [0,8736)
    //   sST  [64][76]  exp(S)      (P3W-P5R)      bytes [0,9728)
    //   stmp [16][76]  tmp         (P4W-P5R)      bytes [9728,12160)
    //   ach  [16][24]  attn_ch     (P3W-P4R)      bytes [12160,12928)
    unsigned short* sxT   = (unsigned short*)smem;
    unsigned short* raw   = (unsigned short*)smem;
    unsigned short* sST   = (unsigned short*)smem;
    unsigned short* stmp  = (unsigned short*)(smem + 9728);
    unsigned short* ach   = (unsigned short*)(smem + 12160);
    unsigned short* soutT = (unsigned short*)(smem + 12928); // [64][100] persistent
    unsigned short* sqkv  = (unsigned short*)(smem + 25728); // [32][64] XOR-swizzled
    unsigned short* qnT   = (unsigned short*)(smem + 29824); // [64][20]
    unsigned short* knT   = (unsigned short*)(smem + 32384); // [64][20]
    unsigned short* vT    = (unsigned short*)(smem + 34944); // [64][20]
    unsigned short* sbias = (unsigned short*)(smem + 37504); // [1352] pre-scaled by log2e

    const int tid  = threadIdx.x;
    const int lane = tid & 63;
    const int g    = tid >> 6;
    const int quad = lane >> 4;
    const int l15  = lane & 15;
    const int wi = blockIdx.x;
    const int y0 = (wi >> 6) << 3;
    const int x0 = (wi & 63) << 3;
    const int py = lane >> 3, px = lane & 7;
    const float L2E = 1.44269504f;

    // ---- stage x^T (bf16) into region X; rel_bias bf16 (pre-scaled by log2e) ----
    for (int r = tid; r < 1536; r += 256) {
        const int c = r >> 4, p0 = (r & 15) * 4;
        float4 v = *(const float4*)(x + c * 262144 + (y0 + (p0 >> 3)) * 512 + x0 + (p0 & 7));
        const unsigned int w0 = pk2bf(v.x, v.y);
        const unsigned int w1 = pk2bf(v.z, v.w);
        sxT[(p0 + 0) * 100 + c] = (unsigned short)w0;
        sxT[(p0 + 1) * 100 + c] = (unsigned short)(w0 >> 16);
        sxT[(p0 + 2) * 100 + c] = (unsigned short)w1;
        sxT[(p0 + 3) * 100 + c] = (unsigned short)(w1 >> 16);
    }
    for (int r = tid; r < 1350; r += 256) sbias[r] = f2bf(rel_bias[r] * L2E);
    __syncthreads();

    // hoist qkv B-fragments (same for all heads)
    short8 bfx[3];
    #pragma unroll
    for (int f = 0; f < 3; ++f)
        bfx[f] = ld_b64x2(sxT + (g * 16 + l15) * 100 + f * 32 + quad * 8);
    __syncthreads();   // region X now reusable

    for (int h = 0; h < 6; ++h) {
        // ---- P1: zero halo ring (27 cells/ch, shared L/R columns); qkv GEMM -> raw ----
        for (int r = tid; r < 1296; r += 256) {
            const int ch = r / 27, k = r % 27;
            int cell;
            if (k < 9)       cell = k;                 // top row
            else if (k < 18) cell = (k - 8) * 9;       // shared left/right column
            else             cell = 82 + (k - 18);     // bottom row
            raw[ch * 91 + cell] = 0;
        }
        {
            const int p = g * 16 + l15;
            const int wcell = (p >> 3) * 9 + (p & 7) + 10;
            #pragma unroll
            for (int t = 0; t < 3; ++t) {
                float4v acc = {0.f, 0.f, 0.f, 0.f};
                #pragma unroll
                for (int f = 0; f < 3; ++f) {
                    short8 af = *(const short8*)(apq + (((t * 6 + h) * 3 + f) * 64 + lane) * 8);
                    acc = mfma16(af, bfx[f], acc);
                }
                const int rr0 = quad * 4;
                const float b0 = acc[0] + qkv_b[t * 96 + h * 16 + rr0 + 0];
                const float b1 = acc[1] + qkv_b[t * 96 + h * 16 + rr0 + 1];
                const float b2 = acc[2] + qkv_b[t * 96 + h * 16 + rr0 + 2];
                const float b3 = acc[3] + qkv_b[t * 96 + h * 16 + rr0 + 3];
                const unsigned int wa = pk2bf(b0, b1);
                const unsigned int wb = pk2bf(b2, b3);
                raw[(t * 16 + rr0 + 0) * 91 + wcell] = (unsigned short)wa;
                raw[(t * 16 + rr0 + 1) * 91 + wcell] = (unsigned short)(wa >> 16);
                raw[(t * 16 + rr0 + 2) * 91 + wcell] = (unsigned short)wb;
                raw[(t * 16 + rr0 + 3) * 91 + wcell] = (unsigned short)(wb >> 16);
            }
        }
        __syncthreads();   // B1

        // ---- P2: dwconv (91-stride halo reads) + L2 norm + transposes ----
        {
            unsigned int qw0 = 0, qw1 = 0, kw0 = 0, kw1 = 0, vw0 = 0, vw1 = 0;
            float aprev = 0.f;
            #pragma unroll
            for (int r = 0; r < 12; ++r) {
                const int j = (r >> 2) * 16 + 4 * g + (r & 3);   // wave-contig rows
                const int O = __builtin_amdgcn_readfirstlane((j >> 4) * 96 + h * 16 + (j & 15));
                const float* wq = dw_w + O * 9;
                float a = dw_b[O];
                const unsigned short* rbase = raw + j * 91 + py * 9 + px;
                a = fmaf(wq[0], bfs(rbase +  0), a);
                a = fmaf(wq[1], bfs(rbase +  1), a);
                a = fmaf(wq[2], bfs(rbase +  2), a);
                a = fmaf(wq[3], bfs(rbase +  9), a);
                a = fmaf(wq[4], bfs(rbase + 10), a);
                a = fmaf(wq[5], bfs(rbase + 11), a);
                a = fmaf(wq[6], bfs(rbase + 18), a);
                a = fmaf(wq[7], bfs(rbase + 19), a);
                a = fmaf(wq[8], bfs(rbase + 20), a);
                if (r < 8) {   // q,k rows: L2-normalize over N=64
                    float ss = a * a;
                    #pragma unroll
                    for (int m = 1; m < 64; m <<= 1) ss += __shfl_xor(ss, m, 64);
                    // 1/max(sqrt(ss),1e-12) == rsq(max(ss,1e-24)); v_rsq 1ulp << bf16 noise
                    a = a * __builtin_amdgcn_rsqf(fmaxf(ss, 1e-24f));
                }
                if (r & 1) {
                    const unsigned int w = pk2bf(aprev, a);   // lo = even r, hi = odd r
                    if (r < 8) {  // ch-major copy for wave0 ch-attn (XOR block swizzle)
                        sqkv[(j - 1) * 64 + (lane ^ (((j - 1) & 7) * 8))] = (unsigned short)w;
                        sqkv[ j      * 64 + (lane ^ (( j      & 7) * 8))] = (unsigned short)(w >> 16);
                    }
                    if      (r == 1)  qw0 = w;
                    else if (r == 3)  qw1 = w;
                    else if (r == 5)  kw0 = w;
                    else if (r == 7)  kw1 = w;
                    else if (r == 9)  vw0 = w;
                    else              vw1 = w;
                } else aprev = a;
            }
            uint2v uq; uq.x = qw0; uq.y = qw1;
            uint2v uk; uk.x = kw0; uk.y = kw1;
            uint2v uv; uv.x = vw0; uv.y = vw1;
            *(uint2v*)(qnT + lane * 20 + 4 * g) = uq;   // stride 20: 4-way (opt) vs 16-way
            *(uint2v*)(knT + lane * 20 + 4 * g) = uk;
            *(uint2v*)(vT  + lane * 20 + 4 * g) = uv;
        }
        __syncthreads();   // B2

        // ---- P3: S^T logits; wave g owns n-block g for ALL m-tiles ->
        //          row sum l[n] completes in-register. exp2(fma) via prescaled bias. ----
        float lsum = 0.f;
        {
            short8 bq = {0, 0, 0, 0, 0, 0, 0, 0};
            if (lane < 32) bq = ld_b64x2(qnT + (g * 16 + l15) * 20 + quad * 8);
            #pragma unroll
            for (int mt = 0; mt < 4; ++mt) {
                short8 ak = {0, 0, 0, 0, 0, 0, 0, 0};
                if (lane < 32) ak = ld_b64x2(knT + (mt * 16 + l15) * 20 + quad * 8);
                float4v cs = {0.f, 0.f, 0.f, 0.f};
                cs = mfma16(ak, bq, cs);
                const int n = g * 16 + l15;
                float e[4];
                #pragma unroll
                for (int reg = 0; reg < 4; ++reg) {
                    const int m = mt * 16 + quad * 4 + reg;
                    const int idx = ((n >> 3) - (m >> 3) + 7) * 15 + ((n & 7) - (m & 7) + 7);
                    e[reg] = exp2f(fmaf(cs[reg], L2E, bfs(sbias + idx * 6 + h)));
                    lsum += e[reg];
                }
                const unsigned int wa = pk2bf(e[0], e[1]);
                const unsigned int wb = pk2bf(e[2], e[3]);
                const int m0 = mt * 16 + quad * 4;
                sST[(m0 + 0) * 76 + n] = (unsigned short)wa;    // stride 76: conflict-free
                sST[(m0 + 1) * 76 + n] = (unsigned short)(wa >> 16);
                sST[(m0 + 2) * 76 + n] = (unsigned short)wb;
                sST[(m0 + 3) * 76 + n] = (unsigned short)(wb >> 16);
            }
            lsum += __shfl_xor(lsum, 16, 64);
            lsum += __shfl_xor(lsum, 32, 64);      // all lanes: l[n], n = g*16+l15
        }
        if (g == 0) {
            const int sw = (l15 & 7) * 8;
            short8 a0 = *(const short8*)(sqkv + l15 * 64 + ((quad * 8) ^ sw));
            short8 a1 = *(const short8*)(sqkv + l15 * 64 + (((quad + 4) * 8) ^ sw));
            short8 b0 = *(const short8*)(sqkv + (16 + l15) * 64 + ((quad * 8) ^ sw));
            short8 b1 = *(const short8*)(sqkv + (16 + l15) * 64 + (((quad + 4) * 8) ^ sw));
            float4v cc = {0.f, 0.f, 0.f, 0.f};
            cc = mfma16(a0, b0, cc);
            cc = mfma16(a1, b1, cc);
            const float tpL = temperature[h] * L2E;
            float er[4];
            #pragma unroll
            for (int reg = 0; reg < 4; ++reg) {
                const float e = exp2f(cc[reg] * tpL);
                float se = e;
                #pragma unroll
                for (int m = 1; m < 16; m <<= 1) se += __shfl_xor(se, m, 64);
                er[reg] = e * __builtin_amdgcn_rcpf(se);
            }
            const unsigned int wa = pk2bf(er[0], er[1]);
            const unsigned int wb = pk2bf(er[2], er[3]);
            ach[(quad * 4 + 0) * 24 + l15] = (unsigned short)wa;
            ach[(quad * 4 + 1) * 24 + l15] = (unsigned short)(wa >> 16);
            ach[(quad * 4 + 2) * 24 + l15] = (unsigned short)wb;
            ach[(quad * 4 + 3) * 24 + l15] = (unsigned short)(wb >> 16);
        }
        __syncthreads();   // B3

        // ---- P4: tmp = (attn_ch @ v) / l[n] -> stmp (l from register, v_rcp) ----
        {
            const float inv = __builtin_amdgcn_rcpf(lsum);
            short8 af = {0, 0, 0, 0, 0, 0, 0, 0}, bv = {0, 0, 0, 0, 0, 0, 0, 0};
            if (lane < 32) {
                af = *(const short8*)(ach + l15 * 24 + quad * 8);
                bv = ld_b64x2(vT + (g * 16 + l15) * 20 + quad * 8);
            }
            float4v ct = {0.f, 0.f, 0.f, 0.f};
            ct = mfma16(af, bv, ct);
            const int n = g * 16 + l15;
            const unsigned int wa = pk2bf(ct[0] * inv, ct[1] * inv);
            const unsigned int wb = pk2bf(ct[2] * inv, ct[3] * inv);
            stmp[(quad * 4 + 0) * 76 + n] = (unsigned short)wa;
            stmp[(quad * 4 + 1) * 76 + n] = (unsigned short)(wa >> 16);
            stmp[(quad * 4 + 2) * 76 + n] = (unsigned short)wb;
            stmp[(quad * 4 + 3) * 76 + n] = (unsigned short)(wb >> 16);
        }
        __syncthreads();   // B4

        // ---- P5: out_h^T = (tmp @ S)^T -> soutT column h (b64 store, 25-chunk
        //          stride -> conflict-free) ----
        {
            short8 a0 = ld_b64x2(stmp + l15 * 76 + quad * 8);
            short8 a1 = ld_b64x2(stmp + l15 * 76 + 32 + quad * 8);
            short8 b0 = ld_b64x2(sST + (g * 16 + l15) * 76 + quad * 8);
            short8 b1 = ld_b64x2(sST + (g * 16 + l15) * 76 + 32 + quad * 8);
            float4v co = {0.f, 0.f, 0.f, 0.f};
            co = mfma16(a0, b0, co);
            co = mfma16(a1, b1, co);
            uint2v w;
            w.x = pk2bf(co[0], co[1]);
            w.y = pk2bf(co[2], co[3]);
            *(uint2v*)(soutT + (g * 16 + l15) * 100 + h * 16 + quad * 4) = w;
        }
        __syncthreads();   // B5 (protects region X for next head)
    }

    // ---- proj GEMM (96x64, K=96) + bias + window-reverse store ----
    {
        short8 pb[3];
        #pragma unroll
        for (int f = 0; f < 3; ++f)
            pb[f] = ld_b64x2(soutT + (g * 16 + l15) * 100 + f * 32 + quad * 8);
        const int p = g * 16 + l15;
        float* outbase = yout + (y0 + (p >> 3)) * 512 + x0 + (p & 7);
        #pragma unroll
        for (int mt = 0; mt < 6; ++mt) {
            float4v acc = {0.f, 0.f, 0.f, 0.f};
            #pragma unroll
            for (int f = 0; f < 3; ++f) {
                short8 af = *(const short8*)(app + ((mt * 3 + f) * 64 + lane) * 8);
                acc = mfma16(af, pb[f], acc);
            }
            #pragma unroll
            for (int reg = 0; reg < 4; ++reg) {
                const int o = mt * 16 + quad * 4 + reg;
                outbase[o * 262144] = acc[reg] + proj_b[o];
            }
        }
    }
}

extern "C" void kernel_launch(void* const* d_in, const int* in_sizes, int n_in,
                              void* d_out, int out_size, void* d_ws, size_t ws_size,
                              hipStream_t stream) {
    const float* x      = (const float*)d_in[0];
    const float* qkv_w  = (const float*)d_in[1];
    const float* qkv_b  = (const float*)d_in[2];
    const float* dw_w   = (const float*)d_in[3];
    const float* dw_b   = (const float*)d_in[4];
    const float* proj_w = (const float*)d_in[5];
    const float* proj_b = (const float*)d_in[6];
    const float* temp   = (const float*)d_in[7];
    const float* relb   = (const float*)d_in[8];
    float* o = (float*)d_out;

    short* apq = (short*)d_ws;              // 27648 bf16
    short* app = apq + 27648;               // 9216 bf16

    hipLaunchKernelGGL(prep_pack, dim3(18), dim3(256), 0, stream, qkv_w, proj_w, apq, app);
    hipLaunchKernelGGL(fused_win_attn, dim3(4096), dim3(256), 0, stream,
                       x, apq, qkv_b, dw_w, dw_b, app, proj_b, temp, relb, o);
}